// Round 1
// baseline (5976.038 us; speedup 1.0000x reference)
//
#include <hip/hip_runtime.h>
#include <hip/hip_bf16.h>
#include <math.h>

// Problem constants (CausalSelfAttention_84928683311105)
#define B_  2
#define T_  2048
#define C_  2048
#define NH_ 16
#define NKV_ 4
#define HD_ 128              // head dim
#define NREP_ (NH_/NKV_)     // 4
// q is scaled by 1/sqrt(HD) in reference, and scores by another 1/sqrt(HD).
#define INV_SQRT_D 0.08838834764831845f

// ---------------------------------------------------------------------------
// fp32 tiled GEMM: C = A(MxK, row-major) @ B(KxN, row-major)
// 64x64 tile, 256 threads, 4x4 microtile, BK=16. Dims assumed multiples.
// ---------------------------------------------------------------------------
#define BM 64
#define BN 64
#define BK 16

__global__ __launch_bounds__(256) void gemm_f32(const float* __restrict__ A,
                                                const float* __restrict__ Bm,
                                                float* __restrict__ Cm,
                                                int M, int N, int K)
{
    __shared__ float As[BK][BM + 4];   // stored transposed: As[k][m]
    __shared__ float Bs[BK][BN + 4];   // Bs[k][n]

    const int tid = threadIdx.x;
    const int tx = tid & 15;           // 0..15 -> n
    const int ty = tid >> 4;           // 0..15 -> m
    const int row0 = blockIdx.y * BM;
    const int col0 = blockIdx.x * BN;

    // A-tile load mapping: 64 rows x 16 k; 4 threads per row, float4 each
    const int aRow = tid >> 2;          // 0..63
    const int aK4  = (tid & 3) * 4;     // 0,4,8,12
    // B-tile load mapping: 16 k-rows x 64 n; 16 threads per row, float4 each
    const int bRow = tid >> 4;          // 0..15
    const int bN4  = (tid & 15) * 4;    // 0..60

    float acc[4][4];
#pragma unroll
    for (int i = 0; i < 4; ++i)
#pragma unroll
        for (int j = 0; j < 4; ++j) acc[i][j] = 0.f;

    for (int k0 = 0; k0 < K; k0 += BK) {
        // load A tile (coalesced along k), store transposed
        float4 av = *(const float4*)&A[(size_t)(row0 + aRow) * K + k0 + aK4];
        As[aK4 + 0][aRow] = av.x;
        As[aK4 + 1][aRow] = av.y;
        As[aK4 + 2][aRow] = av.z;
        As[aK4 + 3][aRow] = av.w;
        // load B tile (coalesced along n)
        float4 bv = *(const float4*)&Bm[(size_t)(k0 + bRow) * N + col0 + bN4];
        *(float4*)&Bs[bRow][bN4] = bv;
        __syncthreads();

#pragma unroll
        for (int kk = 0; kk < BK; ++kk) {
            float4 a4 = *(const float4*)&As[kk][ty * 4];
            float4 b4 = *(const float4*)&Bs[kk][tx * 4];
            float a[4] = {a4.x, a4.y, a4.z, a4.w};
            float b[4] = {b4.x, b4.y, b4.z, b4.w};
#pragma unroll
            for (int i = 0; i < 4; ++i)
#pragma unroll
                for (int j = 0; j < 4; ++j) acc[i][j] += a[i] * b[j];
        }
        __syncthreads();
    }

#pragma unroll
    for (int i = 0; i < 4; ++i) {
        float4 r = make_float4(acc[i][0], acc[i][1], acc[i][2], acc[i][3]);
        *(float4*)&Cm[(size_t)(row0 + ty * 4 + i) * N + col0 + tx * 4] = r;
    }
}

// ---------------------------------------------------------------------------
// RoPE + RMSNorm (+ optional extra scale), one wave (64 lanes) per head vector
// vecs layout: [B,T,nheads,HD] flat. cos/sin: [T, HD/2] flat.
// ---------------------------------------------------------------------------
__global__ __launch_bounds__(256) void rope_rms(float* __restrict__ vecs,
                                                const float* __restrict__ cosb,
                                                const float* __restrict__ sinb,
                                                int nheads, float extra_scale,
                                                int total)
{
    int wid  = blockIdx.x * 4 + (threadIdx.x >> 6);
    if (wid >= total) return;
    int lane = threadIdx.x & 63;
    int t = (wid / nheads) % T_;

    float* p = vecs + ((size_t)wid << 7);   // *128
    float c = cosb[t * 64 + lane];
    float s = sinb[t * 64 + lane];
    float x1 = p[lane];
    float x2 = p[lane + 64];
    float r1 = x1 * c - x2 * s;
    float r2 = x1 * s + x2 * c;
    float ss = r1 * r1 + r2 * r2;
#pragma unroll
    for (int off = 32; off; off >>= 1) ss += __shfl_xor(ss, off, 64);
    float inv = rsqrtf(ss * (1.f / 128.f) + 1e-6f) * extra_scale;
    p[lane]      = r1 * inv;
    p[lane + 64] = r2 * inv;
}

// ---------------------------------------------------------------------------
// Causal attention, GQA. One wave per (b, h, t) query row; streaming softmax.
// q: [B,T,NH,HD], k/v: [B,T,NKV,HD], y: [B,T,NH,HD]
// ---------------------------------------------------------------------------
__global__ __launch_bounds__(256) void attn(const float* __restrict__ q,
                                            const float* __restrict__ k,
                                            const float* __restrict__ v,
                                            float* __restrict__ y)
{
    int wid  = blockIdx.x * 4 + (threadIdx.x >> 6);
    int lane = threadIdx.x & 63;
    int b = wid / (NH_ * T_);
    int r = wid % (NH_ * T_);
    int h = r / T_;
    int t = r % T_;
    int kvh = h / NREP_;

    const float* qp = q + (((size_t)(b * T_ + t) * NH_ + h) << 7);
    float q1 = qp[lane];
    float q2 = qp[lane + 64];

    size_t base = ((size_t)b * T_ * NKV_ + kvh) << 7;   // + s*NKV_*128
    const float* kp = k + base;
    const float* vp = v + base;

    float m = -3.0e38f, l = 0.f, o1 = 0.f, o2 = 0.f;
    for (int s = 0; s <= t; ++s) {
        const float* kr = kp + (size_t)s * (NKV_ * HD_);
        float part = q1 * kr[lane] + q2 * kr[lane + 64];
#pragma unroll
        for (int off = 32; off; off >>= 1) part += __shfl_xor(part, off, 64);
        float score = part * INV_SQRT_D;   // q already carries one 1/sqrt(D)
        float mnew = fmaxf(m, score);
        float corr = __expf(m - mnew);
        float pe   = __expf(score - mnew);
        l = l * corr + pe;
        const float* vr = vp + (size_t)s * (NKV_ * HD_);
        o1 = o1 * corr + pe * vr[lane];
        o2 = o2 * corr + pe * vr[lane + 64];
        m = mnew;
    }
    float invl = 1.f / l;
    float* yp = y + (((size_t)(b * T_ + t) * NH_ + h) << 7);
    yp[lane]      = o1 * invl;
    yp[lane + 64] = o2 * invl;
}

// ---------------------------------------------------------------------------
extern "C" void kernel_launch(void* const* d_in, const int* in_sizes, int n_in,
                              void* d_out, int out_size, void* d_ws, size_t ws_size,
                              hipStream_t stream)
{
    const float* x    = (const float*)d_in[0];
    const float* cosb = (const float*)d_in[1];
    const float* sinb = (const float*)d_in[2];
    const float* Wq   = (const float*)d_in[3];
    const float* Wk   = (const float*)d_in[4];
    const float* Wv   = (const float*)d_in[5];
    const float* Wp   = (const float*)d_in[6];
    float* out = (float*)d_out;

    // workspace layout (floats): q | k | v | y  -> 8.39M + 2.10M + 2.10M + 8.39M = 83.9 MB
    float* q  = (float*)d_ws;
    float* kk = q  + (size_t)B_ * T_ * C_;
    float* vv = kk + (size_t)B_ * T_ * NKV_ * HD_;
    float* y  = vv + (size_t)B_ * T_ * NKV_ * HD_;

    const int M = B_ * T_;   // 4096

    // QKV projections
    gemm_f32<<<dim3(C_ / BN, M / BM), 256, 0, stream>>>(x, Wq, q,  M, C_,          C_);
    gemm_f32<<<dim3((NKV_ * HD_) / BN, M / BM), 256, 0, stream>>>(x, Wk, kk, M, NKV_ * HD_, C_);
    gemm_f32<<<dim3((NKV_ * HD_) / BN, M / BM), 256, 0, stream>>>(x, Wv, vv, M, NKV_ * HD_, C_);

    // RoPE + RMSNorm (+1/sqrt(D) folded into q)
    rope_rms<<<(B_ * T_ * NH_) / 4, 256, 0, stream>>>(q,  cosb, sinb, NH_,  INV_SQRT_D, B_ * T_ * NH_);
    rope_rms<<<(B_ * T_ * NKV_) / 4, 256, 0, stream>>>(kk, cosb, sinb, NKV_, 1.0f,       B_ * T_ * NKV_);

    // causal GQA attention
    attn<<<(B_ * NH_ * T_) / 4, 256, 0, stream>>>(q, kk, vv, y);

    // output projection
    gemm_f32<<<dim3(C_ / BN, M / BM), 256, 0, stream>>>(y, Wp, out, M, C_, C_);
}

// Round 2
// 1543.961 us; speedup vs baseline: 3.8706x; 3.8706x over previous
//
#include <hip/hip_runtime.h>
#include <hip/hip_bf16.h>
#include <math.h>

// Problem constants (CausalSelfAttention_84928683311105)
#define B_  2
#define T_  2048
#define C_  2048
#define NH_ 16
#define NKV_ 4
#define HD_ 128
#define NREP_ (NH_/NKV_)     // 4

typedef __bf16 bf16x8 __attribute__((ext_vector_type(8)));
typedef float  f32x4  __attribute__((ext_vector_type(4)));

// ---------------------------------------------------------------------------
// fp32 tiled GEMM: C = A(MxK) @ B(KxN), row-major; out fp32 or bf16.
// ---------------------------------------------------------------------------
#define BM 64
#define BN 64
#define BK 16

template<typename TOUT>
__global__ __launch_bounds__(256) void gemm_t(const float* __restrict__ A,
                                              const float* __restrict__ Bm,
                                              TOUT* __restrict__ Cm,
                                              int M, int N, int K)
{
    __shared__ float As[BK][BM + 4];
    __shared__ float Bs[BK][BN + 4];

    const int tid = threadIdx.x;
    const int tx = tid & 15;
    const int ty = tid >> 4;
    const int row0 = blockIdx.y * BM;
    const int col0 = blockIdx.x * BN;

    const int aRow = tid >> 2;
    const int aK4  = (tid & 3) * 4;
    const int bRow = tid >> 4;
    const int bN4  = (tid & 15) * 4;

    float acc[4][4];
#pragma unroll
    for (int i = 0; i < 4; ++i)
#pragma unroll
        for (int j = 0; j < 4; ++j) acc[i][j] = 0.f;

    for (int k0 = 0; k0 < K; k0 += BK) {
        float4 av = *(const float4*)&A[(size_t)(row0 + aRow) * K + k0 + aK4];
        As[aK4 + 0][aRow] = av.x;
        As[aK4 + 1][aRow] = av.y;
        As[aK4 + 2][aRow] = av.z;
        As[aK4 + 3][aRow] = av.w;
        float4 bv = *(const float4*)&Bm[(size_t)(k0 + bRow) * N + col0 + bN4];
        *(float4*)&Bs[bRow][bN4] = bv;
        __syncthreads();

#pragma unroll
        for (int kk = 0; kk < BK; ++kk) {
            float4 a4 = *(const float4*)&As[kk][ty * 4];
            float4 b4 = *(const float4*)&Bs[kk][tx * 4];
            float a[4] = {a4.x, a4.y, a4.z, a4.w};
            float b[4] = {b4.x, b4.y, b4.z, b4.w};
#pragma unroll
            for (int i = 0; i < 4; ++i)
#pragma unroll
                for (int j = 0; j < 4; ++j) acc[i][j] += a[i] * b[j];
        }
        __syncthreads();
    }

#pragma unroll
    for (int i = 0; i < 4; ++i) {
        size_t idx = (size_t)(row0 + ty * 4 + i) * N + col0 + tx * 4;
        if constexpr (sizeof(TOUT) == 4) {
            float4 r = make_float4(acc[i][0], acc[i][1], acc[i][2], acc[i][3]);
            *(float4*)&Cm[idx] = r;
        } else {
            union { __bf16 h[4]; uint2 u; } pk;
#pragma unroll
            for (int j = 0; j < 4; ++j) pk.h[j] = (__bf16)acc[i][j];
            *(uint2*)&Cm[idx] = pk.u;
        }
    }
}

// ---------------------------------------------------------------------------
// RoPE + RMSNorm in-place on bf16 vectors. One wave per head-vector.
// scale: extra multiplier folded into output (q gets 1/128 = both sqrt(D)).
// ---------------------------------------------------------------------------
__global__ __launch_bounds__(256) void rope_rms_b(__bf16* __restrict__ vecs,
                                                  const float* __restrict__ cosb,
                                                  const float* __restrict__ sinb,
                                                  int nheads, float scale)
{
    int wid  = blockIdx.x * 4 + (threadIdx.x >> 6);
    int lane = threadIdx.x & 63;
    int t = (wid / nheads) % T_;

    __bf16* p = vecs + ((size_t)wid << 7);
    float c = cosb[t * 64 + lane];
    float s = sinb[t * 64 + lane];
    float x1 = (float)p[lane];
    float x2 = (float)p[lane + 64];
    float r1 = x1 * c - x2 * s;
    float r2 = x1 * s + x2 * c;
    float ss = r1 * r1 + r2 * r2;
#pragma unroll
    for (int off = 32; off; off >>= 1) ss += __shfl_xor(ss, off, 64);
    float inv = rsqrtf(ss * (1.f / 128.f) + 1e-6f) * scale;
    p[lane]      = (__bf16)(r1 * inv);
    p[lane + 64] = (__bf16)(r2 * inv);
}

// ---------------------------------------------------------------------------
// Transpose V: vb [B,T,NKV,128] bf16 -> vt [B,NKV,128,T] bf16.
// One block per (b,kv,32-row s-tile): tile [32 s][128 d].
// ---------------------------------------------------------------------------
__global__ __launch_bounds__(256) void vtrans(const __bf16* __restrict__ vb,
                                              __bf16* __restrict__ vt)
{
    __shared__ __bf16 tl[32][HD_ + 8];   // row stride 272B -> 2-way banks, free
    int bx  = blockIdx.x;                // B*NKV*(T/32) = 512
    int st  = bx & 63;
    int bkv = bx >> 6;
    int b = bkv >> 2, kv = bkv & 3;
    int s0 = st << 5;
    int tid = threadIdx.x;
    {
        int s = tid >> 3;
        int d = (tid & 7) << 4;
        const __bf16* src = vb + (((size_t)(b * T_ + s0 + s) * NKV_ + kv) << 7) + d;
        *(bf16x8*)&tl[s][d]     = *(const bf16x8*)src;
        *(bf16x8*)&tl[s][d + 8] = *(const bf16x8*)(src + 8);
    }
    __syncthreads();
    {
        int d  = tid >> 1;
        int sh = (tid & 1) << 4;
        __bf16 tmp[16];
#pragma unroll
        for (int j = 0; j < 16; ++j) tmp[j] = tl[sh + j][d];
        __bf16* dst = vt + ((size_t)(b * NKV_ + kv) * HD_ + d) * T_ + s0 + sh;
        *(bf16x8*)dst       = *(bf16x8*)&tmp[0];
        *(bf16x8*)(dst + 8) = *(bf16x8*)&tmp[8];
    }
}

// ---------------------------------------------------------------------------
// Flash attention, bf16 MFMA 16x16x32. Block = 4 waves x 16 q-rows = 64 rows
// of one (b,h). K-tiles of 32 staged in LDS; V pre-transposed in global.
// q carries the full 1/128 score scale. y out fp32 [B,T,NH,128].
// ---------------------------------------------------------------------------
#define KT   32
#define QB   64
#define KPAD 136   // K LDS row stride (elems): 272B, bank-friendly
#define VPAD 40    // V^T LDS row stride: 80B
#define PPAD 40    // P LDS row stride: 80B

__global__ __launch_bounds__(256) void attn_mfma(const __bf16* __restrict__ qb,
                                                 const __bf16* __restrict__ kb,
                                                 const __bf16* __restrict__ vbT,
                                                 float* __restrict__ y)
{
    __shared__ __bf16 Ks[KT * KPAD];
    __shared__ __bf16 VTs[HD_ * VPAD];
    __shared__ __bf16 Ps[4][16 * PPAD];

    const int tid  = threadIdx.x;
    const int wv   = tid >> 6;
    const int lane = tid & 63;
    const int grp  = lane >> 4;
    const int id16 = lane & 15;

    const int bx = blockIdx.x;
    const int bh = bx >> 5;             // b*NH + h
    const int b  = bh >> 4;
    const int h  = bh & 15;
    const int kv = h >> 2;
    const int q0 = (31 - (bx & 31)) << 6;   // heavy blocks first
    const int qbase = q0 + (wv << 4);

    // Q fragments (A-layout), 16 rows of this wave
    bf16x8 qf[4];
    {
        const __bf16* qp = qb + (((size_t)(b * T_ + qbase + id16) * NH_ + h) << 7) + (grp << 3);
#pragma unroll
        for (int c = 0; c < 4; ++c) qf[c] = *(const bf16x8*)(qp + c * 32);
    }

    const f32x4 fz = {0.f, 0.f, 0.f, 0.f};
    f32x4 o[8];
#pragma unroll
    for (int c = 0; c < 8; ++c) o[c] = fz;
    float m_r[4], l_r[4];
#pragma unroll
    for (int r = 0; r < 4; ++r) { m_r[r] = -1e30f; l_r[r] = 0.f; }

    const int ntiles = (q0 + QB) / KT;
    const __bf16* kbase  = kb  + (((size_t)b * T_ * NKV_ + kv) << 7);
    const __bf16* vtbase = vbT + ((size_t)(b * NKV_ + kv) * HD_) * T_;

    for (int it = 0; it < ntiles; ++it) {
        const int s0 = it * KT;
        // stage K tile: 32 keys x 128 d
        {
            int r   = tid >> 3;
            int c16 = (tid & 7) << 4;
            const __bf16* src = kbase + (size_t)(s0 + r) * (NKV_ * HD_) + c16;
            *(bf16x8*)&Ks[r * KPAD + c16]     = *(const bf16x8*)src;
            *(bf16x8*)&Ks[r * KPAD + c16 + 8] = *(const bf16x8*)(src + 8);
        }
        // stage V^T tile: 128 d x 32 keys
        {
            int d  = tid >> 1;
            int sh = (tid & 1) << 4;
            const __bf16* src = vtbase + (size_t)d * T_ + s0 + sh;
            *(bf16x8*)&VTs[d * VPAD + sh]     = *(const bf16x8*)src;
            *(bf16x8*)&VTs[d * VPAD + sh + 8] = *(const bf16x8*)(src + 8);
        }
        __syncthreads();

        if (s0 <= qbase + 15) {
            // S[16 rows][32 keys] = Q K^T
            f32x4 S0 = fz, S1 = fz;
#pragma unroll
            for (int c = 0; c < 4; ++c) {
                bf16x8 b0 = *(const bf16x8*)&Ks[id16 * KPAD + c * 32 + (grp << 3)];
                bf16x8 b1 = *(const bf16x8*)&Ks[(id16 + 16) * KPAD + c * 32 + (grp << 3)];
                S0 = __builtin_amdgcn_mfma_f32_16x16x32_bf16(qf[c], b0, S0, 0, 0, 0);
                S1 = __builtin_amdgcn_mfma_f32_16x16x32_bf16(qf[c], b1, S1, 0, 0, 0);
            }
            // causal mask (C layout: row = grp*4+r, col = id16)
            if (s0 + KT - 1 > qbase) {
#pragma unroll
                for (int r = 0; r < 4; ++r) {
                    int q = qbase + (grp << 2) + r;
                    if (s0 + id16 > q)      S0[r] = -1e30f;
                    if (s0 + 16 + id16 > q) S1[r] = -1e30f;
                }
            }
            // online softmax; row stats live across the 16-lane group
            float mnew[4], corr[4];
#pragma unroll
            for (int r = 0; r < 4; ++r) {
                float mx = fmaxf(S0[r], S1[r]);
                mx = fmaxf(mx, __shfl_xor(mx, 1, 64));
                mx = fmaxf(mx, __shfl_xor(mx, 2, 64));
                mx = fmaxf(mx, __shfl_xor(mx, 4, 64));
                mx = fmaxf(mx, __shfl_xor(mx, 8, 64));
                mnew[r] = fmaxf(m_r[r], mx);
                corr[r] = __expf(m_r[r] - mnew[r]);
                m_r[r]  = mnew[r];
            }
            float rs[4];
#pragma unroll
            for (int r = 0; r < 4; ++r) {
                float p0 = __expf(S0[r] - mnew[r]);
                float p1 = __expf(S1[r] - mnew[r]);
                S0[r] = p0; S1[r] = p1;
                rs[r] = p0 + p1;
            }
#pragma unroll
            for (int r = 0; r < 4; ++r) {
                float s = rs[r];
                s += __shfl_xor(s, 1, 64);
                s += __shfl_xor(s, 2, 64);
                s += __shfl_xor(s, 4, 64);
                s += __shfl_xor(s, 8, 64);
                l_r[r] = l_r[r] * corr[r] + s;
            }
            // P (C layout) -> LDS -> A layout
            __bf16* pw = &Ps[wv][0];
#pragma unroll
            for (int r = 0; r < 4; ++r) {
                int row = (grp << 2) + r;
                pw[row * PPAD + id16]      = (__bf16)S0[r];
                pw[row * PPAD + 16 + id16] = (__bf16)S1[r];
            }
            // rescale O
#pragma unroll
            for (int c = 0; c < 8; ++c)
#pragma unroll
                for (int r = 0; r < 4; ++r) o[c][r] *= corr[r];
            asm volatile("s_waitcnt lgkmcnt(0)" ::: "memory");
            bf16x8 pf = *(const bf16x8*)&pw[id16 * PPAD + (grp << 3)];
#pragma unroll
            for (int c = 0; c < 8; ++c) {
                bf16x8 vf = *(const bf16x8*)&VTs[(c * 16 + id16) * VPAD + (grp << 3)];
                o[c] = __builtin_amdgcn_mfma_f32_16x16x32_bf16(pf, vf, o[c], 0, 0, 0);
            }
        }
        __syncthreads();
    }

    // epilogue: y[b, q, h, d] = O / l
    float inv[4];
#pragma unroll
    for (int r = 0; r < 4; ++r) inv[r] = 1.f / l_r[r];
#pragma unroll
    for (int r = 0; r < 4; ++r) {
        int q = qbase + (grp << 2) + r;
        float* yp = y + (((size_t)(b * T_ + q) * NH_ + h) << 7) + id16;
#pragma unroll
        for (int c = 0; c < 8; ++c) yp[c * 16] = o[c][r] * inv[r];
    }
}

// ---------------------------------------------------------------------------
extern "C" void kernel_launch(void* const* d_in, const int* in_sizes, int n_in,
                              void* d_out, int out_size, void* d_ws, size_t ws_size,
                              hipStream_t stream)
{
    const float* x    = (const float*)d_in[0];
    const float* cosb = (const float*)d_in[1];
    const float* sinb = (const float*)d_in[2];
    const float* Wq   = (const float*)d_in[3];
    const float* Wk   = (const float*)d_in[4];
    const float* Wv   = (const float*)d_in[5];
    const float* Wp   = (const float*)d_in[6];
    float* out = (float*)d_out;

    const int M = B_ * T_;   // 4096

    // workspace: qb | kb | vb | vbT (bf16) | y (fp32)  ~= 62.9 MB
    char* w = (char*)d_ws;
    __bf16* qbuf = (__bf16*)w;  w += (size_t)M * C_ * 2;
    __bf16* kbuf = (__bf16*)w;  w += (size_t)M * NKV_ * HD_ * 2;
    __bf16* vbuf = (__bf16*)w;  w += (size_t)M * NKV_ * HD_ * 2;
    __bf16* vtb  = (__bf16*)w;  w += (size_t)M * NKV_ * HD_ * 2;
    float*  y    = (float*)w;

    // QKV projections (fp32 compute, bf16 out)
    gemm_t<__bf16><<<dim3(C_ / BN, M / BM), 256, 0, stream>>>(x, Wq, qbuf, M, C_, C_);
    gemm_t<__bf16><<<dim3((NKV_ * HD_) / BN, M / BM), 256, 0, stream>>>(x, Wk, kbuf, M, NKV_ * HD_, C_);
    gemm_t<__bf16><<<dim3((NKV_ * HD_) / BN, M / BM), 256, 0, stream>>>(x, Wv, vbuf, M, NKV_ * HD_, C_);

    // RoPE + RMSNorm in-place (q gets full 1/128 score scale; exact pow2)
    rope_rms_b<<<(B_ * T_ * NH_) / 4, 256, 0, stream>>>(qbuf, cosb, sinb, NH_, 0.0078125f);
    rope_rms_b<<<(B_ * T_ * NKV_) / 4, 256, 0, stream>>>(kbuf, cosb, sinb, NKV_, 1.0f);

    // V transpose to [B,KV,128,T]
    vtrans<<<B_ * NKV_ * (T_ / 32), 256, 0, stream>>>(vbuf, vtb);

    // flash attention (bf16 MFMA)
    attn_mfma<<<B_ * NH_ * (T_ / QB), 256, 0, stream>>>(qbuf, kbuf, vtb, y);

    // output projection (fp32)
    gemm_t<float><<<dim3(C_ / BN, M / BM), 256, 0, stream>>>(y, Wp, out, M, C_, C_);
}

// Round 3
// 519.018 us; speedup vs baseline: 11.5141x; 2.9748x over previous
//
#include <hip/hip_runtime.h>
#include <hip/hip_bf16.h>
#include <math.h>

// Problem constants (CausalSelfAttention_84928683311105)
#define B_  2
#define T_  2048
#define C_  2048
#define NH_ 16
#define NKV_ 4
#define HD_ 128
#define NREP_ (NH_/NKV_)     // 4

// fused QKV output layout: [B*T, 3072] ; q @ 0, k @ 2048, v @ 2560
#define QKVLD 3072
#define KOFF  2048
#define VOFF  2560

typedef __bf16 bf16x8 __attribute__((ext_vector_type(8)));
typedef float  f32x4  __attribute__((ext_vector_type(4)));

__device__ inline void gload_lds16(const void* g, void* l) {
    __builtin_amdgcn_global_load_lds((const __attribute__((address_space(1))) void*)g,
                                     (__attribute__((address_space(3))) void*)l, 16, 0, 0);
}

// ---------------------------------------------------------------------------
// cast fp32 -> bf16, 8 elems/thread
// ---------------------------------------------------------------------------
__global__ __launch_bounds__(256) void cast_bf16(const float* __restrict__ src,
                                                 __bf16* __restrict__ dst)
{
    size_t i = ((size_t)blockIdx.x * 256 + threadIdx.x) * 8;
    float4 a = *(const float4*)&src[i];
    float4 b = *(const float4*)&src[i + 4];
    union { __bf16 h[8]; uint4 u; } pk;
    pk.h[0] = (__bf16)a.x; pk.h[1] = (__bf16)a.y; pk.h[2] = (__bf16)a.z; pk.h[3] = (__bf16)a.w;
    pk.h[4] = (__bf16)b.x; pk.h[5] = (__bf16)b.y; pk.h[6] = (__bf16)b.z; pk.h[7] = (__bf16)b.w;
    *(uint4*)&dst[i] = pk.u;
}

// ---------------------------------------------------------------------------
// transpose-cast: src fp32 [2048, ncols] -> dst bf16 [ncols, 2048] (row stride 2048)
// 32x32 tiles, 256 threads.
// ---------------------------------------------------------------------------
__global__ __launch_bounds__(256) void wtrans(const float* __restrict__ src,
                                              __bf16* __restrict__ dst, int ncols)
{
    __shared__ float tl[32][33];
    int n0 = blockIdx.x * 32;
    int k0 = blockIdx.y * 32;
    int tid = threadIdx.x;
    int r  = tid >> 3;
    int c4 = (tid & 7) * 4;
    float4 v = *(const float4*)&src[(size_t)(k0 + r) * ncols + n0 + c4];
    tl[r][c4] = v.x; tl[r][c4 + 1] = v.y; tl[r][c4 + 2] = v.z; tl[r][c4 + 3] = v.w;
    __syncthreads();
    union { __bf16 h[4]; uint2 u; } pk;
#pragma unroll
    for (int j = 0; j < 4; ++j) pk.h[j] = (__bf16)tl[c4 + j][r];
    *(uint2*)&dst[(size_t)(n0 + r) * 2048 + k0 + c4] = pk.u;
}

// ---------------------------------------------------------------------------
// bf16 MFMA GEMM (m97 structure): C = A(MxK bf16) @ Bt^T, Bt is [N,K] bf16.
// 128x128 tile, BK=32, 4 waves, global_load_lds(16B), 16x16x32 mfma.
// ---------------------------------------------------------------------------
template<typename TOUT>
__global__ __launch_bounds__(256) void gemm_bt(const __bf16* __restrict__ A,
                                               const __bf16* __restrict__ Bt,
                                               TOUT* __restrict__ C,
                                               int M, int N, int K, int ldc)
{
    __shared__ __bf16 As[128 * 32];   // [m][k]
    __shared__ __bf16 Bs[128 * 32];   // [n][k]

    const int tid  = threadIdx.x;
    const int wv   = tid >> 6;
    const int lane = tid & 63;
    const int grp  = lane >> 4;
    const int id16 = lane & 15;
    const int wr   = wv >> 1;         // wave row (0..1)
    const int wc   = wv & 1;          // wave col (0..1)

    const int row0 = blockIdx.y * 128;
    const int col0 = blockIdx.x * 128;

    // staging mapping: issue covers 64 rows x 32 k; thread -> (row, k8)
    const int sm = tid >> 2;          // 0..63
    const int sk = (tid & 3) << 3;    // 0,8,16,24

    const __bf16* ga0 = A  + (size_t)(row0 + sm) * K + sk;
    const __bf16* ga1 = A  + (size_t)(row0 + 64 + sm) * K + sk;
    const __bf16* gb0 = Bt + (size_t)(col0 + sm) * K + sk;
    const __bf16* gb1 = Bt + (size_t)(col0 + 64 + sm) * K + sk;

    __bf16* lA0 = As + (wv << 9);            // wv*512 elems = wv*1024 B
    __bf16* lA1 = As + 2048 + (wv << 9);
    __bf16* lB0 = Bs + (wv << 9);
    __bf16* lB1 = Bs + 2048 + (wv << 9);

    f32x4 acc[4][4];
    const f32x4 fz = {0.f, 0.f, 0.f, 0.f};
#pragma unroll
    for (int i = 0; i < 4; ++i)
#pragma unroll
        for (int j = 0; j < 4; ++j) acc[i][j] = fz;

    for (int k0 = 0; k0 < K; k0 += 32) {
        gload_lds16(ga0 + k0, lA0);
        gload_lds16(ga1 + k0, lA1);
        gload_lds16(gb0 + k0, lB0);
        gload_lds16(gb1 + k0, lB1);
        asm volatile("s_waitcnt vmcnt(0)" ::: "memory");
        __syncthreads();

        bf16x8 af[4], bfr[4];
#pragma unroll
        for (int i = 0; i < 4; ++i)
            af[i] = *(const bf16x8*)&As[((wr << 6) + (i << 4) + id16) * 32 + (grp << 3)];
#pragma unroll
        for (int j = 0; j < 4; ++j)
            bfr[j] = *(const bf16x8*)&Bs[((wc << 6) + (j << 4) + id16) * 32 + (grp << 3)];
#pragma unroll
        for (int i = 0; i < 4; ++i)
#pragma unroll
            for (int j = 0; j < 4; ++j)
                acc[i][j] = __builtin_amdgcn_mfma_f32_16x16x32_bf16(af[i], bfr[j], acc[i][j], 0, 0, 0);
        __syncthreads();
    }

    // epilogue: C layout col=id16, row=grp*4+r
#pragma unroll
    for (int i = 0; i < 4; ++i) {
        int gr = row0 + (wr << 6) + (i << 4) + (grp << 2);
#pragma unroll
        for (int j = 0; j < 4; ++j) {
            int gc = col0 + (wc << 6) + (j << 4) + id16;
#pragma unroll
            for (int r = 0; r < 4; ++r) {
                if constexpr (sizeof(TOUT) == 4)
                    C[(size_t)(gr + r) * ldc + gc] = acc[i][j][r];
                else
                    C[(size_t)(gr + r) * ldc + gc] = (TOUT)acc[i][j][r];
            }
        }
    }
}

// ---------------------------------------------------------------------------
// RoPE + RMSNorm in-place on bf16 head-vectors inside the strided qkv buffer.
// ---------------------------------------------------------------------------
__global__ __launch_bounds__(256) void rope_rms_b(__bf16* __restrict__ base,
                                                  const float* __restrict__ cosb,
                                                  const float* __restrict__ sinb,
                                                  int nheads, float scale)
{
    int wid  = blockIdx.x * 4 + (threadIdx.x >> 6);
    int lane = threadIdx.x & 63;
    int bt = wid / nheads;
    int hd = wid % nheads;
    int t  = bt % T_;

    __bf16* p = base + (size_t)bt * QKVLD + hd * HD_;
    float c = cosb[t * 64 + lane];
    float s = sinb[t * 64 + lane];
    float x1 = (float)p[lane];
    float x2 = (float)p[lane + 64];
    float r1 = x1 * c - x2 * s;
    float r2 = x1 * s + x2 * c;
    float ss = r1 * r1 + r2 * r2;
#pragma unroll
    for (int off = 32; off; off >>= 1) ss += __shfl_xor(ss, off, 64);
    float inv = rsqrtf(ss * (1.f / 128.f) + 1e-6f) * scale;
    p[lane]      = (__bf16)(r1 * inv);
    p[lane + 64] = (__bf16)(r2 * inv);
}

// ---------------------------------------------------------------------------
// Transpose V out of qkv: -> vt [B,NKV,128,T] bf16.
// ---------------------------------------------------------------------------
__global__ __launch_bounds__(256) void vtrans(const __bf16* __restrict__ qkv,
                                              __bf16* __restrict__ vt)
{
    __shared__ __bf16 tl[32][HD_ + 8];
    int bx  = blockIdx.x;                // B*NKV*(T/32) = 512
    int st  = bx & 63;
    int bkv = bx >> 6;
    int b = bkv >> 2, kv = bkv & 3;
    int s0 = st << 5;
    int tid = threadIdx.x;
    {
        int s = tid >> 3;
        int d = (tid & 7) << 4;
        const __bf16* src = qkv + (size_t)(b * T_ + s0 + s) * QKVLD + VOFF + kv * HD_ + d;
        *(bf16x8*)&tl[s][d]     = *(const bf16x8*)src;
        *(bf16x8*)&tl[s][d + 8] = *(const bf16x8*)(src + 8);
    }
    __syncthreads();
    {
        int d  = tid >> 1;
        int sh = (tid & 1) << 4;
        __bf16 tmp[16];
#pragma unroll
        for (int j = 0; j < 16; ++j) tmp[j] = tl[sh + j][d];
        __bf16* dst = vt + ((size_t)(b * NKV_ + kv) * HD_ + d) * T_ + s0 + sh;
        *(bf16x8*)dst       = *(bf16x8*)&tmp[0];
        *(bf16x8*)(dst + 8) = *(bf16x8*)&tmp[8];
    }
}

// ---------------------------------------------------------------------------
// Flash attention, bf16 MFMA 16x16x32. Block = 4 waves x 16 q-rows.
// Reads q/k from strided qkv buffer; writes bf16 y [B*T, 2048].
// ---------------------------------------------------------------------------
#define KT   32
#define QB   64
#define KPAD 136
#define VPAD 40
#define PPAD 40

__global__ __launch_bounds__(256) void attn_mfma(const __bf16* __restrict__ qkv,
                                                 const __bf16* __restrict__ vbT,
                                                 __bf16* __restrict__ y)
{
    __shared__ __bf16 Ks[KT * KPAD];
    __shared__ __bf16 VTs[HD_ * VPAD];
    __shared__ __bf16 Ps[4][16 * PPAD];

    const int tid  = threadIdx.x;
    const int wv   = tid >> 6;
    const int lane = tid & 63;
    const int grp  = lane >> 4;
    const int id16 = lane & 15;

    const int bx = blockIdx.x;
    const int bh = bx >> 5;
    const int b  = bh >> 4;
    const int h  = bh & 15;
    const int kv = h >> 2;
    const int q0 = (31 - (bx & 31)) << 6;
    const int qbase = q0 + (wv << 4);

    bf16x8 qf[4];
    {
        const __bf16* qp = qkv + (size_t)(b * T_ + qbase + id16) * QKVLD + h * HD_ + (grp << 3);
#pragma unroll
        for (int c = 0; c < 4; ++c) qf[c] = *(const bf16x8*)(qp + c * 32);
    }

    const f32x4 fz = {0.f, 0.f, 0.f, 0.f};
    f32x4 o[8];
#pragma unroll
    for (int c = 0; c < 8; ++c) o[c] = fz;
    float m_r[4], l_r[4];
#pragma unroll
    for (int r = 0; r < 4; ++r) { m_r[r] = -1e30f; l_r[r] = 0.f; }

    const int ntiles = (q0 + QB) / KT;
    const __bf16* kbase  = qkv + (size_t)b * T_ * QKVLD + KOFF + kv * HD_;
    const __bf16* vtbase = vbT + ((size_t)(b * NKV_ + kv) * HD_) * T_;

    for (int it = 0; it < ntiles; ++it) {
        const int s0 = it * KT;
        {
            int r   = tid >> 3;
            int c16 = (tid & 7) << 4;
            const __bf16* src = kbase + (size_t)(s0 + r) * QKVLD + c16;
            *(bf16x8*)&Ks[r * KPAD + c16]     = *(const bf16x8*)src;
            *(bf16x8*)&Ks[r * KPAD + c16 + 8] = *(const bf16x8*)(src + 8);
        }
        {
            int d  = tid >> 1;
            int sh = (tid & 1) << 4;
            const __bf16* src = vtbase + (size_t)d * T_ + s0 + sh;
            *(bf16x8*)&VTs[d * VPAD + sh]     = *(const bf16x8*)src;
            *(bf16x8*)&VTs[d * VPAD + sh + 8] = *(const bf16x8*)(src + 8);
        }
        __syncthreads();

        if (s0 <= qbase + 15) {
            f32x4 S0 = fz, S1 = fz;
#pragma unroll
            for (int c = 0; c < 4; ++c) {
                bf16x8 b0 = *(const bf16x8*)&Ks[id16 * KPAD + c * 32 + (grp << 3)];
                bf16x8 b1 = *(const bf16x8*)&Ks[(id16 + 16) * KPAD + c * 32 + (grp << 3)];
                S0 = __builtin_amdgcn_mfma_f32_16x16x32_bf16(qf[c], b0, S0, 0, 0, 0);
                S1 = __builtin_amdgcn_mfma_f32_16x16x32_bf16(qf[c], b1, S1, 0, 0, 0);
            }
            if (s0 + KT - 1 > qbase) {
#pragma unroll
                for (int r = 0; r < 4; ++r) {
                    int q = qbase + (grp << 2) + r;
                    if (s0 + id16 > q)      S0[r] = -1e30f;
                    if (s0 + 16 + id16 > q) S1[r] = -1e30f;
                }
            }
            float mnew[4], corr[4];
#pragma unroll
            for (int r = 0; r < 4; ++r) {
                float mx = fmaxf(S0[r], S1[r]);
                mx = fmaxf(mx, __shfl_xor(mx, 1, 64));
                mx = fmaxf(mx, __shfl_xor(mx, 2, 64));
                mx = fmaxf(mx, __shfl_xor(mx, 4, 64));
                mx = fmaxf(mx, __shfl_xor(mx, 8, 64));
                mnew[r] = fmaxf(m_r[r], mx);
                corr[r] = __expf(m_r[r] - mnew[r]);
                m_r[r]  = mnew[r];
            }
            float rs[4];
#pragma unroll
            for (int r = 0; r < 4; ++r) {
                float p0 = __expf(S0[r] - mnew[r]);
                float p1 = __expf(S1[r] - mnew[r]);
                S0[r] = p0; S1[r] = p1;
                rs[r] = p0 + p1;
            }
#pragma unroll
            for (int r = 0; r < 4; ++r) {
                float s = rs[r];
                s += __shfl_xor(s, 1, 64);
                s += __shfl_xor(s, 2, 64);
                s += __shfl_xor(s, 4, 64);
                s += __shfl_xor(s, 8, 64);
                l_r[r] = l_r[r] * corr[r] + s;
            }
            __bf16* pw = &Ps[wv][0];
#pragma unroll
            for (int r = 0; r < 4; ++r) {
                int row = (grp << 2) + r;
                pw[row * PPAD + id16]      = (__bf16)S0[r];
                pw[row * PPAD + 16 + id16] = (__bf16)S1[r];
            }
#pragma unroll
            for (int c = 0; c < 8; ++c)
#pragma unroll
                for (int r = 0; r < 4; ++r) o[c][r] *= corr[r];
            asm volatile("s_waitcnt lgkmcnt(0)" ::: "memory");
            bf16x8 pf = *(const bf16x8*)&pw[id16 * PPAD + (grp << 3)];
#pragma unroll
            for (int c = 0; c < 8; ++c) {
                bf16x8 vf = *(const bf16x8*)&VTs[(c * 16 + id16) * VPAD + (grp << 3)];
                o[c] = __builtin_amdgcn_mfma_f32_16x16x32_bf16(pf, vf, o[c], 0, 0, 0);
            }
        }
        __syncthreads();
    }

    float inv[4];
#pragma unroll
    for (int r = 0; r < 4; ++r) inv[r] = 1.f / l_r[r];
#pragma unroll
    for (int r = 0; r < 4; ++r) {
        int q = qbase + (grp << 2) + r;
        __bf16* yp = y + (size_t)(b * T_ + q) * C_ + h * HD_ + id16;
#pragma unroll
        for (int c = 0; c < 8; ++c) yp[c * 16] = (__bf16)(o[c][r] * inv[r]);
    }
}

// ---------------------------------------------------------------------------
extern "C" void kernel_launch(void* const* d_in, const int* in_sizes, int n_in,
                              void* d_out, int out_size, void* d_ws, size_t ws_size,
                              hipStream_t stream)
{
    const float* x    = (const float*)d_in[0];
    const float* cosb = (const float*)d_in[1];
    const float* sinb = (const float*)d_in[2];
    const float* Wq   = (const float*)d_in[3];
    const float* Wk   = (const float*)d_in[4];
    const float* Wv   = (const float*)d_in[5];
    const float* Wp   = (const float*)d_in[6];
    float* out = (float*)d_out;

    const int M = B_ * T_;   // 4096

    // workspace: xb | qkv | wqkvT | wpT | vt | y   (all bf16)  ~= 84 MB
    char* w = (char*)d_ws;
    __bf16* xb    = (__bf16*)w;  w += (size_t)M * C_ * 2;            // 16.8 MB
    __bf16* qkv   = (__bf16*)w;  w += (size_t)M * QKVLD * 2;         // 25.2 MB
    __bf16* wqkvT = (__bf16*)w;  w += (size_t)QKVLD * C_ * 2;        // 12.6 MB
    __bf16* wpT   = (__bf16*)w;  w += (size_t)C_ * C_ * 2;           //  8.4 MB
    __bf16* vt    = (__bf16*)w;  w += (size_t)M * NKV_ * HD_ * 2;    //  4.2 MB
    __bf16* y     = (__bf16*)w;                                      // 16.8 MB

    // casts / transposes
    cast_bf16<<<(M * C_) / 2048, 256, 0, stream>>>(x, xb);
    wtrans<<<dim3(C_ / 32, C_ / 32), 256, 0, stream>>>(Wq, wqkvT, C_);
    wtrans<<<dim3(512 / 32, C_ / 32), 256, 0, stream>>>(Wk, wqkvT + (size_t)KOFF * C_, 512);
    wtrans<<<dim3(512 / 32, C_ / 32), 256, 0, stream>>>(Wv, wqkvT + (size_t)VOFF * C_, 512);
    wtrans<<<dim3(C_ / 32, C_ / 32), 256, 0, stream>>>(Wp, wpT, C_);

    // fused QKV projection (bf16 MFMA)
    gemm_bt<__bf16><<<dim3(QKVLD / 128, M / 128), 256, 0, stream>>>(xb, wqkvT, qkv, M, QKVLD, C_, QKVLD);

    // RoPE + RMSNorm in-place (q gets full 1/128 score scale; exact pow2)
    rope_rms_b<<<(M * NH_) / 4, 256, 0, stream>>>(qkv, cosb, sinb, NH_, 0.0078125f);
    rope_rms_b<<<(M * NKV_) / 4, 256, 0, stream>>>(qkv + KOFF, cosb, sinb, NKV_, 1.0f);

    // V transpose to [B,KV,128,T]
    vtrans<<<B_ * NKV_ * (T_ / 32), 256, 0, stream>>>(qkv, vt);

    // flash attention (bf16 MFMA), bf16 y out
    attn_mfma<<<B_ * NH_ * (T_ / QB), 256, 0, stream>>>(qkv, vt, y);

    // output projection (bf16 MFMA, fp32 out)
    gemm_bt<float><<<dim3(C_ / 128, M / 128), 256, 0, stream>>>(y, wpT, out, M, C_, C_, C_);
}

// Round 4
// 356.453 us; speedup vs baseline: 16.7653x; 1.4561x over previous
//
#include <hip/hip_runtime.h>
#include <hip/hip_bf16.h>
#include <math.h>

// Problem constants (CausalSelfAttention_84928683311105)
#define B_  2
#define T_  2048
#define C_  2048
#define NH_ 16
#define NKV_ 4
#define HD_ 128
#define NREP_ (NH_/NKV_)     // 4

// fused QKV output layout: [B*T, 3072] ; q @ 0, k @ 2048, v @ 2560
#define QKVLD 3072
#define KOFF  2048
#define VOFF  2560

typedef __bf16 bf16x8 __attribute__((ext_vector_type(8)));
typedef float  f32x4  __attribute__((ext_vector_type(4)));

__device__ inline void gload_lds16(const void* g, void* l) {
    __builtin_amdgcn_global_load_lds((const __attribute__((address_space(1))) void*)g,
                                     (__attribute__((address_space(3))) void*)l, 16, 0, 0);
}

// ---------------------------------------------------------------------------
// cast fp32 -> bf16, 8 elems/thread
// ---------------------------------------------------------------------------
__global__ __launch_bounds__(256) void cast_bf16(const float* __restrict__ src,
                                                 __bf16* __restrict__ dst)
{
    size_t i = ((size_t)blockIdx.x * 256 + threadIdx.x) * 8;
    float4 a = *(const float4*)&src[i];
    float4 b = *(const float4*)&src[i + 4];
    union { __bf16 h[8]; uint4 u; } pk;
    pk.h[0] = (__bf16)a.x; pk.h[1] = (__bf16)a.y; pk.h[2] = (__bf16)a.z; pk.h[3] = (__bf16)a.w;
    pk.h[4] = (__bf16)b.x; pk.h[5] = (__bf16)b.y; pk.h[6] = (__bf16)b.z; pk.h[7] = (__bf16)b.w;
    *(uint4*)&dst[i] = pk.u;
}

// ---------------------------------------------------------------------------
// transpose-cast: src fp32 [2048, ncols] -> dst bf16 [ncols, 2048]
// ---------------------------------------------------------------------------
__global__ __launch_bounds__(256) void wtrans(const float* __restrict__ src,
                                              __bf16* __restrict__ dst, int ncols)
{
    __shared__ float tl[32][33];
    int n0 = blockIdx.x * 32;
    int k0 = blockIdx.y * 32;
    int tid = threadIdx.x;
    int r  = tid >> 3;
    int c4 = (tid & 7) * 4;
    float4 v = *(const float4*)&src[(size_t)(k0 + r) * ncols + n0 + c4];
    tl[r][c4] = v.x; tl[r][c4 + 1] = v.y; tl[r][c4 + 2] = v.z; tl[r][c4 + 3] = v.w;
    __syncthreads();
    union { __bf16 h[4]; uint2 u; } pk;
#pragma unroll
    for (int j = 0; j < 4; ++j) pk.h[j] = (__bf16)tl[c4 + j][r];
    *(uint2*)&dst[(size_t)(n0 + r) * 2048 + k0 + c4] = pk.u;
}

// ---------------------------------------------------------------------------
// bf16 MFMA GEMM (m97 structure): C = A(MxK bf16) @ Bt^T, Bt is [N,K] bf16.
// ---------------------------------------------------------------------------
template<typename TOUT>
__global__ __launch_bounds__(256) void gemm_bt(const __bf16* __restrict__ A,
                                               const __bf16* __restrict__ Bt,
                                               TOUT* __restrict__ C,
                                               int M, int N, int K, int ldc)
{
    __shared__ __bf16 As[128 * 32];   // [m][k]
    __shared__ __bf16 Bs[128 * 32];   // [n][k]

    const int tid  = threadIdx.x;
    const int wv   = tid >> 6;
    const int lane = tid & 63;
    const int grp  = lane >> 4;
    const int id16 = lane & 15;
    const int wr   = wv >> 1;
    const int wc   = wv & 1;

    const int row0 = blockIdx.y * 128;
    const int col0 = blockIdx.x * 128;

    const int sm = tid >> 2;
    const int sk = (tid & 3) << 3;

    const __bf16* ga0 = A  + (size_t)(row0 + sm) * K + sk;
    const __bf16* ga1 = A  + (size_t)(row0 + 64 + sm) * K + sk;
    const __bf16* gb0 = Bt + (size_t)(col0 + sm) * K + sk;
    const __bf16* gb1 = Bt + (size_t)(col0 + 64 + sm) * K + sk;

    __bf16* lA0 = As + (wv << 9);
    __bf16* lA1 = As + 2048 + (wv << 9);
    __bf16* lB0 = Bs + (wv << 9);
    __bf16* lB1 = Bs + 2048 + (wv << 9);

    f32x4 acc[4][4];
    const f32x4 fz = {0.f, 0.f, 0.f, 0.f};
#pragma unroll
    for (int i = 0; i < 4; ++i)
#pragma unroll
        for (int j = 0; j < 4; ++j) acc[i][j] = fz;

    for (int k0 = 0; k0 < K; k0 += 32) {
        gload_lds16(ga0 + k0, lA0);
        gload_lds16(ga1 + k0, lA1);
        gload_lds16(gb0 + k0, lB0);
        gload_lds16(gb1 + k0, lB1);
        asm volatile("s_waitcnt vmcnt(0)" ::: "memory");
        __syncthreads();

        bf16x8 af[4], bfr[4];
#pragma unroll
        for (int i = 0; i < 4; ++i)
            af[i] = *(const bf16x8*)&As[((wr << 6) + (i << 4) + id16) * 32 + (grp << 3)];
#pragma unroll
        for (int j = 0; j < 4; ++j)
            bfr[j] = *(const bf16x8*)&Bs[((wc << 6) + (j << 4) + id16) * 32 + (grp << 3)];
#pragma unroll
        for (int i = 0; i < 4; ++i)
#pragma unroll
            for (int j = 0; j < 4; ++j)
                acc[i][j] = __builtin_amdgcn_mfma_f32_16x16x32_bf16(af[i], bfr[j], acc[i][j], 0, 0, 0);
        __syncthreads();
    }

#pragma unroll
    for (int i = 0; i < 4; ++i) {
        int gr = row0 + (wr << 6) + (i << 4) + (grp << 2);
#pragma unroll
        for (int j = 0; j < 4; ++j) {
            int gc = col0 + (wc << 6) + (j << 4) + id16;
#pragma unroll
            for (int r = 0; r < 4; ++r) {
                if constexpr (sizeof(TOUT) == 4)
                    C[(size_t)(gr + r) * ldc + gc] = acc[i][j][r];
                else
                    C[(size_t)(gr + r) * ldc + gc] = (TOUT)acc[i][j][r];
            }
        }
    }
}

// ---------------------------------------------------------------------------
// RoPE + RMSNorm in-place on bf16 head-vectors inside the strided qkv buffer.
// ---------------------------------------------------------------------------
__global__ __launch_bounds__(256) void rope_rms_b(__bf16* __restrict__ base,
                                                  const float* __restrict__ cosb,
                                                  const float* __restrict__ sinb,
                                                  int nheads, float scale)
{
    int wid  = blockIdx.x * 4 + (threadIdx.x >> 6);
    int lane = threadIdx.x & 63;
    int bt = wid / nheads;
    int hd = wid % nheads;
    int t  = bt % T_;

    __bf16* p = base + (size_t)bt * QKVLD + hd * HD_;
    float c = cosb[t * 64 + lane];
    float s = sinb[t * 64 + lane];
    float x1 = (float)p[lane];
    float x2 = (float)p[lane + 64];
    float r1 = x1 * c - x2 * s;
    float r2 = x1 * s + x2 * c;
    float ss = r1 * r1 + r2 * r2;
#pragma unroll
    for (int off = 32; off; off >>= 1) ss += __shfl_xor(ss, off, 64);
    float inv = rsqrtf(ss * (1.f / 128.f) + 1e-6f) * scale;
    p[lane]      = (__bf16)(r1 * inv);
    p[lane + 64] = (__bf16)(r2 * inv);
}

// ---------------------------------------------------------------------------
// Transpose V out of qkv: -> vt [B,NKV,128,T] bf16.
// ---------------------------------------------------------------------------
__global__ __launch_bounds__(256) void vtrans(const __bf16* __restrict__ qkv,
                                              __bf16* __restrict__ vt)
{
    __shared__ __bf16 tl[32][HD_ + 8];
    int bx  = blockIdx.x;
    int st  = bx & 63;
    int bkv = bx >> 6;
    int b = bkv >> 2, kv = bkv & 3;
    int s0 = st << 5;
    int tid = threadIdx.x;
    {
        int s = tid >> 3;
        int d = (tid & 7) << 4;
        const __bf16* src = qkv + (size_t)(b * T_ + s0 + s) * QKVLD + VOFF + kv * HD_ + d;
        *(bf16x8*)&tl[s][d]     = *(const bf16x8*)src;
        *(bf16x8*)&tl[s][d + 8] = *(const bf16x8*)(src + 8);
    }
    __syncthreads();
    {
        int d  = tid >> 1;
        int sh = (tid & 1) << 4;
        __bf16 tmp[16];
#pragma unroll
        for (int j = 0; j < 16; ++j) tmp[j] = tl[sh + j][d];
        __bf16* dst = vt + ((size_t)(b * NKV_ + kv) * HD_ + d) * T_ + s0 + sh;
        *(bf16x8*)dst       = *(bf16x8*)&tmp[0];
        *(bf16x8*)(dst + 8) = *(bf16x8*)&tmp[8];
    }
}

// ---------------------------------------------------------------------------
// Flash attention v2: KT=64 double-buffered global_load_lds staging with XOR
// swizzle; block = one (b,h) x paired q-tiles (j, 31-j) of 64 rows each.
// All blocks do exactly 33 key-tiles -> perfectly balanced. Grid 512.
// K LDS layout: row=key (128 elems), 16B chunk p stores logical chunk
// p^(key&15). V^T LDS: row=d (64 elems), chunk p stores logical p^(d&7).
// ---------------------------------------------------------------------------
#define KT2 64
#define PP  72

__global__ __launch_bounds__(256) void attn_mfma2(const __bf16* __restrict__ qkv,
                                                  const __bf16* __restrict__ vbT,
                                                  __bf16* __restrict__ y)
{
    __shared__ __bf16 Ks[2][KT2 * 128];
    __shared__ __bf16 VTs[2][128 * KT2];
    __shared__ __bf16 Ps[4][16 * PP];

    const int tid  = threadIdx.x;
    const int wv   = tid >> 6;
    const int lane = tid & 63;
    const int grp  = lane >> 4;
    const int id16 = lane & 15;

    const int bx = blockIdx.x;          // 512 = (B*NH) * 16
    const int j  = bx & 15;
    const int bh = bx >> 4;
    const int b  = bh >> 4;
    const int h  = bh & 15;
    const int kv = h >> 2;

    const int q0a = j << 6;             // phase-0 q-tile base
    const int q0b = (31 - j) << 6;      // phase-1 q-tile base
    const int NTa = j + 1;              // phase-0 tile count (KT2 keys each)
    const int NT  = 33;                 // total (NTa + 32 - j)

    // per-lane staging byte offsets (swizzled)
    const int l4 = lane >> 4, l8 = lane >> 3;
    size_t koff[4], voff[4];
#pragma unroll
    for (int i = 0; i < 4; ++i) {
        int key = wv * 16 + i * 4 + l4;
        int ch  = (lane & 15) ^ (i * 4 + l4);
        koff[i] = (size_t)key * (QKVLD * 2) + ch * 16;
        int d   = wv * 32 + i * 8 + l8;
        int ch2 = (lane & 7) ^ l8;
        voff[i] = (size_t)d * (T_ * 2) + ch2 * 16;
    }
    const char* kg = (const char*)(qkv + (size_t)b * T_ * QKVLD + KOFF + kv * HD_);
    const char* vg = (const char*)(vbT + ((size_t)(b * NKV_ + kv) * HD_) * T_);

    // Q fragments for both phases (phase-1 copied over at switch)
    bf16x8 qf[4], qf2[4];
    {
        const __bf16* qp = qkv + (size_t)(b * T_ + q0a + wv * 16 + id16) * QKVLD + h * HD_ + (grp << 3);
#pragma unroll
        for (int c = 0; c < 4; ++c) qf[c] = *(const bf16x8*)(qp + c * 32);
        const __bf16* qp2 = qkv + (size_t)(b * T_ + q0b + wv * 16 + id16) * QKVLD + h * HD_ + (grp << 3);
#pragma unroll
        for (int c = 0; c < 4; ++c) qf2[c] = *(const bf16x8*)(qp2 + c * 32);
    }

    const f32x4 fz = {0.f, 0.f, 0.f, 0.f};
    f32x4 o[8];
#pragma unroll
    for (int c = 0; c < 8; ++c) o[c] = fz;
    float m_r[4], l_r[4];
#pragma unroll
    for (int r = 0; r < 4; ++r) { m_r[r] = -1e30f; l_r[r] = 0.f; }

    int qbase = q0a + wv * 16;
    int q0c   = q0a;

    // stage tile 0 into buf 0
    {
        __bf16* kl = &Ks[0][(wv * 16) * 128];
        __bf16* vl = &VTs[0][(wv * 32) * 64];
#pragma unroll
        for (int i = 0; i < 4; ++i) gload_lds16(kg + koff[i], kl + i * 4 * 128);
#pragma unroll
        for (int i = 0; i < 4; ++i) gload_lds16(vg + voff[i], vl + i * 8 * 64);
    }

    for (int tt = 0; tt < NT; ++tt) {
        const int bufc = tt & 1;
        asm volatile("s_waitcnt vmcnt(0)" ::: "memory");
        __syncthreads();

        // prefetch next tile into the other buffer
        if (tt + 1 < NT) {
            int tn = tt + 1;
            int sn = (tn >= NTa ? tn - NTa : tn) << 6;
            __bf16* kl = &Ks[tn & 1][(wv * 16) * 128];
            __bf16* vl = &VTs[tn & 1][(wv * 32) * 64];
            const char* kp = kg + (size_t)sn * (QKVLD * 2);
            const char* vp = vg + (size_t)sn * 2;
#pragma unroll
            for (int i = 0; i < 4; ++i) gload_lds16(kp + koff[i], kl + i * 4 * 128);
#pragma unroll
            for (int i = 0; i < 4; ++i) gload_lds16(vp + voff[i], vl + i * 8 * 64);
        }

        // phase switch: write out phase-0 output, reset state
        if (tt == NTa) {
            float inv[4];
#pragma unroll
            for (int r = 0; r < 4; ++r) inv[r] = 1.f / l_r[r];
#pragma unroll
            for (int r = 0; r < 4; ++r) {
                int q = qbase + (grp << 2) + r;
                __bf16* yp = y + (size_t)(b * T_ + q) * C_ + h * HD_ + id16;
#pragma unroll
                for (int c = 0; c < 8; ++c) yp[c * 16] = (__bf16)(o[c][r] * inv[r]);
            }
#pragma unroll
            for (int c = 0; c < 8; ++c) o[c] = fz;
#pragma unroll
            for (int r = 0; r < 4; ++r) { m_r[r] = -1e30f; l_r[r] = 0.f; }
#pragma unroll
            for (int c = 0; c < 4; ++c) qf[c] = qf2[c];
            qbase = q0b + wv * 16;
            q0c   = q0b;
        }

        const int s0 = (tt >= NTa ? tt - NTa : tt) << 6;

        // ---- QK^T: S[16 rows][64 keys] ----
        f32x4 S[4];
#pragma unroll
        for (int t = 0; t < 4; ++t) S[t] = fz;
#pragma unroll
        for (int c = 0; c < 4; ++c) {
#pragma unroll
            for (int t = 0; t < 4; ++t) {
                bf16x8 kf = *(const bf16x8*)&Ks[bufc][(t * 16 + id16) * 128 + ((((c << 2) + grp) ^ id16) << 3)];
                S[t] = __builtin_amdgcn_mfma_f32_16x16x32_bf16(qf[c], kf, S[t], 0, 0, 0);
            }
        }
        // causal mask: only the last tile of a phase crosses the diagonal
        if (s0 == q0c) {
#pragma unroll
            for (int t = 0; t < 4; ++t)
#pragma unroll
                for (int r = 0; r < 4; ++r)
                    if (s0 + t * 16 + id16 > qbase + (grp << 2) + r) S[t][r] = -1e30f;
        }

        // ---- online softmax (row stats across id16 lanes) ----
        float corr[4];
#pragma unroll
        for (int r = 0; r < 4; ++r) {
            float mx = fmaxf(fmaxf(S[0][r], S[1][r]), fmaxf(S[2][r], S[3][r]));
            mx = fmaxf(mx, __shfl_xor(mx, 1, 64));
            mx = fmaxf(mx, __shfl_xor(mx, 2, 64));
            mx = fmaxf(mx, __shfl_xor(mx, 4, 64));
            mx = fmaxf(mx, __shfl_xor(mx, 8, 64));
            float mn = fmaxf(m_r[r], mx);
            corr[r] = __expf(m_r[r] - mn);
            m_r[r]  = mn;
            float rs = 0.f;
#pragma unroll
            for (int t = 0; t < 4; ++t) {
                float p = __expf(S[t][r] - mn);
                S[t][r] = p;
                rs += p;
            }
            rs += __shfl_xor(rs, 1, 64);
            rs += __shfl_xor(rs, 2, 64);
            rs += __shfl_xor(rs, 4, 64);
            rs += __shfl_xor(rs, 8, 64);
            l_r[r] = l_r[r] * corr[r] + rs;
        }

        // ---- P (C layout) -> LDS -> A layout ----
        __bf16* pw = Ps[wv];
#pragma unroll
        for (int t = 0; t < 4; ++t)
#pragma unroll
            for (int r = 0; r < 4; ++r)
                pw[((grp << 2) + r) * PP + t * 16 + id16] = (__bf16)S[t][r];

        // rescale O while P stores land
#pragma unroll
        for (int c = 0; c < 8; ++c)
#pragma unroll
            for (int r = 0; r < 4; ++r) o[c][r] *= corr[r];

        asm volatile("s_waitcnt lgkmcnt(0)" ::: "memory");
        bf16x8 pf0 = *(const bf16x8*)&pw[id16 * PP + (grp << 3)];
        bf16x8 pf1 = *(const bf16x8*)&pw[id16 * PP + 32 + (grp << 3)];

        // ---- PV: O[16][128] += P[16][64] V[64][128] ----
#pragma unroll
        for (int c2 = 0; c2 < 8; ++c2) {
            bf16x8 vf0 = *(const bf16x8*)&VTs[bufc][(c2 * 16 + id16) * 64 + ((grp ^ (id16 & 7)) << 3)];
            o[c2] = __builtin_amdgcn_mfma_f32_16x16x32_bf16(pf0, vf0, o[c2], 0, 0, 0);
            bf16x8 vf1 = *(const bf16x8*)&VTs[bufc][(c2 * 16 + id16) * 64 + (((4 + grp) ^ (id16 & 7)) << 3)];
            o[c2] = __builtin_amdgcn_mfma_f32_16x16x32_bf16(pf1, vf1, o[c2], 0, 0, 0);
        }
    }

    // final epilogue (phase 1)
    {
        float inv[4];
#pragma unroll
        for (int r = 0; r < 4; ++r) inv[r] = 1.f / l_r[r];
#pragma unroll
        for (int r = 0; r < 4; ++r) {
            int q = qbase + (grp << 2) + r;
            __bf16* yp = y + (size_t)(b * T_ + q) * C_ + h * HD_ + id16;
#pragma unroll
            for (int c = 0; c < 8; ++c) yp[c * 16] = (__bf16)(o[c][r] * inv[r]);
        }
    }
}

// ---------------------------------------------------------------------------
extern "C" void kernel_launch(void* const* d_in, const int* in_sizes, int n_in,
                              void* d_out, int out_size, void* d_ws, size_t ws_size,
                              hipStream_t stream)
{
    const float* x    = (const float*)d_in[0];
    const float* cosb = (const float*)d_in[1];
    const float* sinb = (const float*)d_in[2];
    const float* Wq   = (const float*)d_in[3];
    const float* Wk   = (const float*)d_in[4];
    const float* Wv   = (const float*)d_in[5];
    const float* Wp   = (const float*)d_in[6];
    float* out = (float*)d_out;

    const int M = B_ * T_;   // 4096

    // workspace: xb | qkv | wqkvT | wpT | vt | y   (all bf16)  ~= 84 MB
    char* w = (char*)d_ws;
    __bf16* xb    = (__bf16*)w;  w += (size_t)M * C_ * 2;
    __bf16* qkv   = (__bf16*)w;  w += (size_t)M * QKVLD * 2;
    __bf16* wqkvT = (__bf16*)w;  w += (size_t)QKVLD * C_ * 2;
    __bf16* wpT   = (__bf16*)w;  w += (size_t)C_ * C_ * 2;
    __bf16* vt    = (__bf16*)w;  w += (size_t)M * NKV_ * HD_ * 2;
    __bf16* y     = (__bf16*)w;

    // casts / transposes
    cast_bf16<<<(M * C_) / 2048, 256, 0, stream>>>(x, xb);
    wtrans<<<dim3(C_ / 32, C_ / 32), 256, 0, stream>>>(Wq, wqkvT, C_);
    wtrans<<<dim3(512 / 32, C_ / 32), 256, 0, stream>>>(Wk, wqkvT + (size_t)KOFF * C_, 512);
    wtrans<<<dim3(512 / 32, C_ / 32), 256, 0, stream>>>(Wv, wqkvT + (size_t)VOFF * C_, 512);
    wtrans<<<dim3(C_ / 32, C_ / 32), 256, 0, stream>>>(Wp, wpT, C_);

    // fused QKV projection (bf16 MFMA)
    gemm_bt<__bf16><<<dim3(QKVLD / 128, M / 128), 256, 0, stream>>>(xb, wqkvT, qkv, M, QKVLD, C_, QKVLD);

    // RoPE + RMSNorm in-place (q gets full 1/128 score scale; exact pow2)
    rope_rms_b<<<(M * NH_) / 4, 256, 0, stream>>>(qkv, cosb, sinb, NH_, 0.0078125f);
    rope_rms_b<<<(M * NKV_) / 4, 256, 0, stream>>>(qkv + KOFF, cosb, sinb, NKV_, 1.0f);

    // V transpose to [B,KV,128,T]
    vtrans<<<B_ * NKV_ * (T_ / 32), 256, 0, stream>>>(qkv, vt);

    // flash attention v2 (bf16 MFMA, dbuf, swizzled staging), bf16 y out
    attn_mfma2<<<B_ * NH_ * 16, 256, 0, stream>>>(qkv, vt, y);

    // output projection (bf16 MFMA, fp32 out)
    gemm_bt<float><<<dim3(C_ / 128, M / 128), 256, 0, stream>>>(y, wpT, out, M, C_, C_, C_);
}

// Round 5
// 320.865 us; speedup vs baseline: 18.6248x; 1.1109x over previous
//
#include <hip/hip_runtime.h>
#include <hip/hip_bf16.h>
#include <math.h>

// Problem constants (CausalSelfAttention_84928683311105)
#define B_  2
#define T_  2048
#define C_  2048
#define NH_ 16
#define NKV_ 4
#define HD_ 128
#define NREP_ (NH_/NKV_)     // 4

// fused QKV output layout: [B*T, 3072] ; q @ 0, k @ 2048, v @ 2560
#define QKVLD 3072
#define KOFF  2048
#define VOFF  2560

// q scale: (1/sqrt(d))^2 folded = 1/128, times log2(e) so scores are in
// log2 units and softmax exp is a single native v_exp_f32.
#define QSCALE 0.01127105500694502f

typedef __bf16 bf16x8 __attribute__((ext_vector_type(8)));
typedef float  f32x4  __attribute__((ext_vector_type(4)));

__device__ inline void gload_lds16(const void* g, void* l) {
    __builtin_amdgcn_global_load_lds((const __attribute__((address_space(1))) void*)g,
                                     (__attribute__((address_space(3))) void*)l, 16, 0, 0);
}

// ---------------------------------------------------------------------------
// cast fp32 -> bf16, 8 elems/thread
// ---------------------------------------------------------------------------
__global__ __launch_bounds__(256) void cast_bf16(const float* __restrict__ src,
                                                 __bf16* __restrict__ dst)
{
    size_t i = ((size_t)blockIdx.x * 256 + threadIdx.x) * 8;
    float4 a = *(const float4*)&src[i];
    float4 b = *(const float4*)&src[i + 4];
    union { __bf16 h[8]; uint4 u; } pk;
    pk.h[0] = (__bf16)a.x; pk.h[1] = (__bf16)a.y; pk.h[2] = (__bf16)a.z; pk.h[3] = (__bf16)a.w;
    pk.h[4] = (__bf16)b.x; pk.h[5] = (__bf16)b.y; pk.h[6] = (__bf16)b.z; pk.h[7] = (__bf16)b.w;
    *(uint4*)&dst[i] = pk.u;
}

// ---------------------------------------------------------------------------
// merged transpose-cast of Wq|Wk|Wv into wqkvT [3072, 2048] bf16.
// col-tile ct: 0..63 -> Wq (ncols 2048), 64..79 -> Wk, 80..95 -> Wv.
// ---------------------------------------------------------------------------
__global__ __launch_bounds__(256) void wtrans_qkv(const float* __restrict__ Wq,
                                                  const float* __restrict__ Wk,
                                                  const float* __restrict__ Wv,
                                                  __bf16* __restrict__ dst)
{
    __shared__ float tl[32][33];
    int ct = blockIdx.x;
    int k0 = blockIdx.y * 32;
    const float* src;
    int ncols, c0, dr0;
    if (ct < 64)      { src = Wq; ncols = 2048; c0 = ct * 32;        dr0 = ct * 32; }
    else if (ct < 80) { src = Wk; ncols = 512;  c0 = (ct - 64) * 32; dr0 = KOFF + (ct - 64) * 32; }
    else              { src = Wv; ncols = 512;  c0 = (ct - 80) * 32; dr0 = VOFF + (ct - 80) * 32; }

    int tid = threadIdx.x;
    int r  = tid >> 3;
    int c4 = (tid & 7) * 4;
    float4 v = *(const float4*)&src[(size_t)(k0 + r) * ncols + c0 + c4];
    tl[r][c4] = v.x; tl[r][c4 + 1] = v.y; tl[r][c4 + 2] = v.z; tl[r][c4 + 3] = v.w;
    __syncthreads();
    union { __bf16 h[4]; uint2 u; } pk;
#pragma unroll
    for (int j = 0; j < 4; ++j) pk.h[j] = (__bf16)tl[c4 + j][r];
    *(uint2*)&dst[(size_t)(dr0 + r) * 2048 + k0 + c4] = pk.u;
}

// plain transpose-cast for Wp
__global__ __launch_bounds__(256) void wtrans(const float* __restrict__ src,
                                              __bf16* __restrict__ dst, int ncols)
{
    __shared__ float tl[32][33];
    int n0 = blockIdx.x * 32;
    int k0 = blockIdx.y * 32;
    int tid = threadIdx.x;
    int r  = tid >> 3;
    int c4 = (tid & 7) * 4;
    float4 v = *(const float4*)&src[(size_t)(k0 + r) * ncols + n0 + c4];
    tl[r][c4] = v.x; tl[r][c4 + 1] = v.y; tl[r][c4 + 2] = v.z; tl[r][c4 + 3] = v.w;
    __syncthreads();
    union { __bf16 h[4]; uint2 u; } pk;
#pragma unroll
    for (int j = 0; j < 4; ++j) pk.h[j] = (__bf16)tl[c4 + j][r];
    *(uint2*)&dst[(size_t)(n0 + r) * 2048 + k0 + c4] = pk.u;
}

// ---------------------------------------------------------------------------
// bf16 MFMA GEMM, single-barrier double-buffered: C = A(MxK) @ Bt^T, Bt [N,K].
// 128x128 tile, BK=32, 4 waves, global_load_lds(16B) prefetch into alt buffer.
// ---------------------------------------------------------------------------
template<typename TOUT>
__global__ __launch_bounds__(256) void gemm_bt(const __bf16* __restrict__ A,
                                               const __bf16* __restrict__ Bt,
                                               TOUT* __restrict__ C,
                                               int M, int N, int K, int ldc)
{
    __shared__ __bf16 As[2][128 * 32];   // [m][k]
    __shared__ __bf16 Bs[2][128 * 32];   // [n][k]

    const int tid  = threadIdx.x;
    const int wv   = tid >> 6;
    const int lane = tid & 63;
    const int grp  = lane >> 4;
    const int id16 = lane & 15;
    const int wr   = wv >> 1;
    const int wc   = wv & 1;

    const int row0 = blockIdx.y * 128;
    const int col0 = blockIdx.x * 128;

    const int sm = tid >> 2;
    const int sk = (tid & 3) << 3;

    const __bf16* ga0 = A  + (size_t)(row0 + sm) * K + sk;
    const __bf16* ga1 = A  + (size_t)(row0 + 64 + sm) * K + sk;
    const __bf16* gb0 = Bt + (size_t)(col0 + sm) * K + sk;
    const __bf16* gb1 = Bt + (size_t)(col0 + 64 + sm) * K + sk;

    f32x4 acc[4][4];
    const f32x4 fz = {0.f, 0.f, 0.f, 0.f};
#pragma unroll
    for (int i = 0; i < 4; ++i)
#pragma unroll
        for (int j = 0; j < 4; ++j) acc[i][j] = fz;

    const int nk = K >> 5;

    // prologue: stage tile 0 into buf 0
    {
        __bf16* a0 = &As[0][wv << 9];
        __bf16* b0 = &Bs[0][wv << 9];
        gload_lds16(ga0, a0);
        gload_lds16(ga1, a0 + 2048);
        gload_lds16(gb0, b0);
        gload_lds16(gb1, b0 + 2048);
    }

    for (int kt = 0; kt < nk; ++kt) {
        const int bufc = kt & 1;
        asm volatile("s_waitcnt vmcnt(0)" ::: "memory");
        __syncthreads();

        if (kt + 1 < nk) {
            const int kb = (kt + 1) << 5;
            __bf16* a0 = &As[1 - bufc][wv << 9];
            __bf16* b0 = &Bs[1 - bufc][wv << 9];
            gload_lds16(ga0 + kb, a0);
            gload_lds16(ga1 + kb, a0 + 2048);
            gload_lds16(gb0 + kb, b0);
            gload_lds16(gb1 + kb, b0 + 2048);
        }

        bf16x8 af[4], bfr[4];
#pragma unroll
        for (int i = 0; i < 4; ++i)
            af[i] = *(const bf16x8*)&As[bufc][((wr << 6) + (i << 4) + id16) * 32 + (grp << 3)];
#pragma unroll
        for (int j = 0; j < 4; ++j)
            bfr[j] = *(const bf16x8*)&Bs[bufc][((wc << 6) + (j << 4) + id16) * 32 + (grp << 3)];
#pragma unroll
        for (int i = 0; i < 4; ++i)
#pragma unroll
            for (int j = 0; j < 4; ++j)
                acc[i][j] = __builtin_amdgcn_mfma_f32_16x16x32_bf16(af[i], bfr[j], acc[i][j], 0, 0, 0);
    }

#pragma unroll
    for (int i = 0; i < 4; ++i) {
        int gr = row0 + (wr << 6) + (i << 4) + (grp << 2);
#pragma unroll
        for (int j = 0; j < 4; ++j) {
            int gc = col0 + (wc << 6) + (j << 4) + id16;
#pragma unroll
            for (int r = 0; r < 4; ++r) {
                if constexpr (sizeof(TOUT) == 4)
                    C[(size_t)(gr + r) * ldc + gc] = acc[i][j][r];
                else
                    C[(size_t)(gr + r) * ldc + gc] = (TOUT)acc[i][j][r];
            }
        }
    }
}

// ---------------------------------------------------------------------------
// RoPE + RMSNorm in-place on bf16 head-vectors inside the strided qkv buffer.
// ---------------------------------------------------------------------------
__global__ __launch_bounds__(256) void rope_rms_b(__bf16* __restrict__ base,
                                                  const float* __restrict__ cosb,
                                                  const float* __restrict__ sinb,
                                                  int nheads, float scale)
{
    int wid  = blockIdx.x * 4 + (threadIdx.x >> 6);
    int lane = threadIdx.x & 63;
    int bt = wid / nheads;
    int hd = wid % nheads;
    int t  = bt % T_;

    __bf16* p = base + (size_t)bt * QKVLD + hd * HD_;
    float c = cosb[t * 64 + lane];
    float s = sinb[t * 64 + lane];
    float x1 = (float)p[lane];
    float x2 = (float)p[lane + 64];
    float r1 = x1 * c - x2 * s;
    float r2 = x1 * s + x2 * c;
    float ss = r1 * r1 + r2 * r2;
#pragma unroll
    for (int off = 32; off; off >>= 1) ss += __shfl_xor(ss, off, 64);
    float inv = rsqrtf(ss * (1.f / 128.f) + 1e-6f) * scale;
    p[lane]      = (__bf16)(r1 * inv);
    p[lane + 64] = (__bf16)(r2 * inv);
}

// ---------------------------------------------------------------------------
// Transpose V out of qkv: -> vt [B,NKV,128,T] bf16.
// ---------------------------------------------------------------------------
__global__ __launch_bounds__(256) void vtrans(const __bf16* __restrict__ qkv,
                                              __bf16* __restrict__ vt)
{
    __shared__ __bf16 tl[32][HD_ + 8];
    int bx  = blockIdx.x;
    int st  = bx & 63;
    int bkv = bx >> 6;
    int b = bkv >> 2, kv = bkv & 3;
    int s0 = st << 5;
    int tid = threadIdx.x;
    {
        int s = tid >> 3;
        int d = (tid & 7) << 4;
        const __bf16* src = qkv + (size_t)(b * T_ + s0 + s) * QKVLD + VOFF + kv * HD_ + d;
        *(bf16x8*)&tl[s][d]     = *(const bf16x8*)src;
        *(bf16x8*)&tl[s][d + 8] = *(const bf16x8*)(src + 8);
    }
    __syncthreads();
    {
        int d  = tid >> 1;
        int sh = (tid & 1) << 4;
        __bf16 tmp[16];
#pragma unroll
        for (int j = 0; j < 16; ++j) tmp[j] = tl[sh + j][d];
        __bf16* dst = vt + ((size_t)(b * NKV_ + kv) * HD_ + d) * T_ + s0 + sh;
        *(bf16x8*)dst       = *(bf16x8*)&tmp[0];
        *(bf16x8*)(dst + 8) = *(bf16x8*)&tmp[8];
    }
}

// ---------------------------------------------------------------------------
// Flash attention v3: fixed-max softmax. Scores are exactly bounded |s|<=1
// (Cauchy-Schwarz on RMS-normalized q,k), so no running max / rescale is
// needed: p = exp2(S) directly (q carries 1/128*log2e), l accumulated as
// per-lane partials, reduced once per phase. KT=64 dbuf + XOR swizzle as R4.
// ---------------------------------------------------------------------------
#define KT2 64
#define PP  72

__global__ __launch_bounds__(256) void attn_mfma2(const __bf16* __restrict__ qkv,
                                                  const __bf16* __restrict__ vbT,
                                                  __bf16* __restrict__ y)
{
    __shared__ __bf16 Ks[2][KT2 * 128];
    __shared__ __bf16 VTs[2][128 * KT2];
    __shared__ __bf16 Ps[4][16 * PP];

    const int tid  = threadIdx.x;
    const int wv   = tid >> 6;
    const int lane = tid & 63;
    const int grp  = lane >> 4;
    const int id16 = lane & 15;

    const int bx = blockIdx.x;          // 512 = (B*NH) * 16
    const int j  = bx & 15;
    const int bh = bx >> 4;
    const int b  = bh >> 4;
    const int h  = bh & 15;
    const int kv = h >> 2;

    const int q0a = j << 6;
    const int q0b = (31 - j) << 6;
    const int NTa = j + 1;
    const int NT  = 33;

    const int l4 = lane >> 4, l8 = lane >> 3;
    size_t koff[4], voff[4];
#pragma unroll
    for (int i = 0; i < 4; ++i) {
        int key = wv * 16 + i * 4 + l4;
        int ch  = (lane & 15) ^ (i * 4 + l4);
        koff[i] = (size_t)key * (QKVLD * 2) + ch * 16;
        int d   = wv * 32 + i * 8 + l8;
        int ch2 = (lane & 7) ^ l8;
        voff[i] = (size_t)d * (T_ * 2) + ch2 * 16;
    }
    const char* kg = (const char*)(qkv + (size_t)b * T_ * QKVLD + KOFF + kv * HD_);
    const char* vg = (const char*)(vbT + ((size_t)(b * NKV_ + kv) * HD_) * T_);

    bf16x8 qf[4], qf2[4];
    {
        const __bf16* qp = qkv + (size_t)(b * T_ + q0a + wv * 16 + id16) * QKVLD + h * HD_ + (grp << 3);
#pragma unroll
        for (int c = 0; c < 4; ++c) qf[c] = *(const bf16x8*)(qp + c * 32);
        const __bf16* qp2 = qkv + (size_t)(b * T_ + q0b + wv * 16 + id16) * QKVLD + h * HD_ + (grp << 3);
#pragma unroll
        for (int c = 0; c < 4; ++c) qf2[c] = *(const bf16x8*)(qp2 + c * 32);
    }

    const f32x4 fz = {0.f, 0.f, 0.f, 0.f};
    f32x4 o[8];
#pragma unroll
    for (int c = 0; c < 8; ++c) o[c] = fz;
    float l_r[4];
#pragma unroll
    for (int r = 0; r < 4; ++r) l_r[r] = 0.f;

    int qbase = q0a + wv * 16;
    int q0c   = q0a;

    {
        __bf16* kl = &Ks[0][(wv * 16) * 128];
        __bf16* vl = &VTs[0][(wv * 32) * 64];
#pragma unroll
        for (int i = 0; i < 4; ++i) gload_lds16(kg + koff[i], kl + i * 4 * 128);
#pragma unroll
        for (int i = 0; i < 4; ++i) gload_lds16(vg + voff[i], vl + i * 8 * 64);
    }

    for (int tt = 0; tt < NT; ++tt) {
        const int bufc = tt & 1;
        asm volatile("s_waitcnt vmcnt(0)" ::: "memory");
        __syncthreads();

        if (tt + 1 < NT) {
            int tn = tt + 1;
            int sn = (tn >= NTa ? tn - NTa : tn) << 6;
            __bf16* kl = &Ks[tn & 1][(wv * 16) * 128];
            __bf16* vl = &VTs[tn & 1][(wv * 32) * 64];
            const char* kp = kg + (size_t)sn * (QKVLD * 2);
            const char* vp = vg + (size_t)sn * 2;
#pragma unroll
            for (int i = 0; i < 4; ++i) gload_lds16(kp + koff[i], kl + i * 4 * 128);
#pragma unroll
            for (int i = 0; i < 4; ++i) gload_lds16(vp + voff[i], vl + i * 8 * 64);
        }

        // phase switch: write out phase-0 output, reset state
        if (tt == NTa) {
            float inv[4];
#pragma unroll
            for (int r = 0; r < 4; ++r) {
                float l = l_r[r];
                l += __shfl_xor(l, 1, 64);
                l += __shfl_xor(l, 2, 64);
                l += __shfl_xor(l, 4, 64);
                l += __shfl_xor(l, 8, 64);
                inv[r] = 1.f / l;
            }
#pragma unroll
            for (int r = 0; r < 4; ++r) {
                int q = qbase + (grp << 2) + r;
                __bf16* yp = y + (size_t)(b * T_ + q) * C_ + h * HD_ + id16;
#pragma unroll
                for (int c = 0; c < 8; ++c) yp[c * 16] = (__bf16)(o[c][r] * inv[r]);
            }
#pragma unroll
            for (int c = 0; c < 8; ++c) o[c] = fz;
#pragma unroll
            for (int r = 0; r < 4; ++r) l_r[r] = 0.f;
#pragma unroll
            for (int c = 0; c < 4; ++c) qf[c] = qf2[c];
            qbase = q0b + wv * 16;
            q0c   = q0b;
        }

        const int s0 = (tt >= NTa ? tt - NTa : tt) << 6;

        // ---- QK^T: S[16 rows][64 keys] (log2 units) ----
        f32x4 S[4];
#pragma unroll
        for (int t = 0; t < 4; ++t) S[t] = fz;
#pragma unroll
        for (int c = 0; c < 4; ++c) {
#pragma unroll
            for (int t = 0; t < 4; ++t) {
                bf16x8 kf = *(const bf16x8*)&Ks[bufc][(t * 16 + id16) * 128 + ((((c << 2) + grp) ^ id16) << 3)];
                S[t] = __builtin_amdgcn_mfma_f32_16x16x32_bf16(qf[c], kf, S[t], 0, 0, 0);
            }
        }
        if (s0 == q0c) {
#pragma unroll
            for (int t = 0; t < 4; ++t)
#pragma unroll
                for (int r = 0; r < 4; ++r)
                    if (s0 + t * 16 + id16 > qbase + (grp << 2) + r) S[t][r] = -1e30f;
        }

        // ---- softmax numerators: p = exp2(S), per-lane l partials ----
#pragma unroll
        for (int t = 0; t < 4; ++t)
#pragma unroll
            for (int r = 0; r < 4; ++r) S[t][r] = exp2f(S[t][r]);
#pragma unroll
        for (int r = 0; r < 4; ++r)
            l_r[r] += (S[0][r] + S[1][r]) + (S[2][r] + S[3][r]);

        // ---- P (C layout) -> LDS -> A layout ----
        __bf16* pw = Ps[wv];
#pragma unroll
        for (int t = 0; t < 4; ++t)
#pragma unroll
            for (int r = 0; r < 4; ++r)
                pw[((grp << 2) + r) * PP + t * 16 + id16] = (__bf16)S[t][r];

        asm volatile("s_waitcnt lgkmcnt(0)" ::: "memory");
        bf16x8 pf0 = *(const bf16x8*)&pw[id16 * PP + (grp << 3)];
        bf16x8 pf1 = *(const bf16x8*)&pw[id16 * PP + 32 + (grp << 3)];

        // ---- PV: O[16][128] += P[16][64] V[64][128] ----
#pragma unroll
        for (int c2 = 0; c2 < 8; ++c2) {
            bf16x8 vf0 = *(const bf16x8*)&VTs[bufc][(c2 * 16 + id16) * 64 + ((grp ^ (id16 & 7)) << 3)];
            o[c2] = __builtin_amdgcn_mfma_f32_16x16x32_bf16(pf0, vf0, o[c2], 0, 0, 0);
            bf16x8 vf1 = *(const bf16x8*)&VTs[bufc][(c2 * 16 + id16) * 64 + (((4 + grp) ^ (id16 & 7)) << 3)];
            o[c2] = __builtin_amdgcn_mfma_f32_16x16x32_bf16(pf1, vf1, o[c2], 0, 0, 0);
        }
    }

    // final epilogue (phase 1)
    {
        float inv[4];
#pragma unroll
        for (int r = 0; r < 4; ++r) {
            float l = l_r[r];
            l += __shfl_xor(l, 1, 64);
            l += __shfl_xor(l, 2, 64);
            l += __shfl_xor(l, 4, 64);
            l += __shfl_xor(l, 8, 64);
            inv[r] = 1.f / l;
        }
#pragma unroll
        for (int r = 0; r < 4; ++r) {
            int q = qbase + (grp << 2) + r;
            __bf16* yp = y + (size_t)(b * T_ + q) * C_ + h * HD_ + id16;
#pragma unroll
            for (int c = 0; c < 8; ++c) yp[c * 16] = (__bf16)(o[c][r] * inv[r]);
        }
    }
}

// ---------------------------------------------------------------------------
extern "C" void kernel_launch(void* const* d_in, const int* in_sizes, int n_in,
                              void* d_out, int out_size, void* d_ws, size_t ws_size,
                              hipStream_t stream)
{
    const float* x    = (const float*)d_in[0];
    const float* cosb = (const float*)d_in[1];
    const float* sinb = (const float*)d_in[2];
    const float* Wq   = (const float*)d_in[3];
    const float* Wk   = (const float*)d_in[4];
    const float* Wv   = (const float*)d_in[5];
    const float* Wp   = (const float*)d_in[6];
    float* out = (float*)d_out;

    const int M = B_ * T_;   // 4096

    // workspace: xb | qkv | wqkvT | wpT | vt | y   (all bf16)  ~= 84 MB
    char* w = (char*)d_ws;
    __bf16* xb    = (__bf16*)w;  w += (size_t)M * C_ * 2;
    __bf16* qkv   = (__bf16*)w;  w += (size_t)M * QKVLD * 2;
    __bf16* wqkvT = (__bf16*)w;  w += (size_t)QKVLD * C_ * 2;
    __bf16* wpT   = (__bf16*)w;  w += (size_t)C_ * C_ * 2;
    __bf16* vt    = (__bf16*)w;  w += (size_t)M * NKV_ * HD_ * 2;
    __bf16* y     = (__bf16*)w;

    // casts / transposes
    cast_bf16<<<(M * C_) / 2048, 256, 0, stream>>>(x, xb);
    wtrans_qkv<<<dim3(96, C_ / 32), 256, 0, stream>>>(Wq, Wk, Wv, wqkvT);
    wtrans<<<dim3(C_ / 32, C_ / 32), 256, 0, stream>>>(Wp, wpT, C_);

    // fused QKV projection (bf16 MFMA, dbuf)
    gemm_bt<__bf16><<<dim3(QKVLD / 128, M / 128), 256, 0, stream>>>(xb, wqkvT, qkv, M, QKVLD, C_, QKVLD);

    // RoPE + RMSNorm in-place (q gets 1/128 * log2e; k plain)
    rope_rms_b<<<(M * NH_) / 4, 256, 0, stream>>>(qkv, cosb, sinb, NH_, QSCALE);
    rope_rms_b<<<(M * NKV_) / 4, 256, 0, stream>>>(qkv + KOFF, cosb, sinb, NKV_, 1.0f);

    // V transpose to [B,KV,128,T]
    vtrans<<<B_ * NKV_ * (T_ / 32), 256, 0, stream>>>(qkv, vt);

    // flash attention v3 (fixed-max softmax), bf16 y out
    attn_mfma2<<<B_ * NH_ * 16, 256, 0, stream>>>(qkv, vt, y);

    // output projection (bf16 MFMA, fp32 out, dbuf)
    gemm_bt<float><<<dim3(C_ / 128, M / 128), 256, 0, stream>>>(y, wpT, out, M, C_, C_, C_);
}